// Round 2
// baseline (4117.052 us; speedup 1.0000x reference)
//
#include <hip/hip_runtime.h>

typedef __attribute__((ext_vector_type(8))) short bf16x8;
typedef __attribute__((ext_vector_type(4))) float f32x4;

#define NBLK 256

// ---------- helpers ----------
__device__ __forceinline__ unsigned short f2bf(float f) {
  unsigned u = __float_as_uint(f);
  unsigned r = u + 0x7fffu + ((u >> 16) & 1u);   // RNE
  return (unsigned short)(r >> 16);
}
__device__ __forceinline__ float bf2f(unsigned short h) {
  return __uint_as_float(((unsigned)h) << 16);
}
// packed = (hi_bits<<16) | lo_bits  (weights only)
__device__ __forceinline__ unsigned pack_split(float f) {
  unsigned short hi = f2bf(f);
  float res = f - bf2f(hi);
  unsigned short lo = f2bf(res);
  return (((unsigned)hi) << 16) | (unsigned)lo;
}
// 8 packed elems (2x uint4) -> hi-frag / lo-frag (weight reg-load only)
__device__ __forceinline__ void unpack2(uint4 a0, uint4 a1, bf16x8& hi, bf16x8& lo) {
  union { bf16x8 v; unsigned u[4]; } H, L;
  H.u[0] = (a0.x >> 16) | (a0.y & 0xffff0000u);
  L.u[0] = (a0.x & 0xffffu) | (a0.y << 16);
  H.u[1] = (a0.z >> 16) | (a0.w & 0xffff0000u);
  L.u[1] = (a0.z & 0xffffu) | (a0.w << 16);
  H.u[2] = (a1.x >> 16) | (a1.y & 0xffff0000u);
  L.u[2] = (a1.x & 0xffffu) | (a1.y << 16);
  H.u[3] = (a1.z >> 16) | (a1.w & 0xffff0000u);
  L.u[3] = (a1.z & 0xffffu) | (a1.w << 16);
  hi = H.v; lo = L.v;
}
union U4B { uint4 u; bf16x8 b; };
__device__ __forceinline__ bf16x8 as_bf(uint4 u) { U4B x; x.u = u; return x.b; }
__device__ __forceinline__ float sigm(float x) { return 1.0f / (1.0f + __expf(-x)); }
__device__ __forceinline__ float tanh_f(float x) { return 1.0f - 2.0f / (__expf(2.0f * x) + 1.0f); }

// ---------- prep ----------
// Weights (unchanged from verified r1 mapping):
// wreg[wg=256][wave=8][l=2][kt=8][lane=64][e=8] packed dwords;
// kloc = wv*128 + (kt&3)*32 + q*8 + e ; kt<4 -> W_hh, else W_ih.
// Activation slabs are hi/lo-SEPARATED: [row][512 hi-dwords][512 lo-dwords],
// dword j<512 holds hi(e=2j),hi(2j+1); j>=512 holds lo parts.
__global__ __launch_bounds__(256) void prep_kernel(
    const float* __restrict__ wih, const float* __restrict__ whh,
    const float* __restrict__ wfc_in, const float* __restrict__ hin,
    unsigned* __restrict__ wreg, unsigned* __restrict__ wfc, unsigned* __restrict__ xinit) {
  for (int e0 = 0; e0 < 8; ++e0) {
    unsigned idx = blockIdx.x * 2048u + (unsigned)e0 * 256u + threadIdx.x;
    if (idx < 16777216u) {
      unsigned wg   = idx >> 16;
      unsigned r    = idx & 65535u;
      unsigned wv   = r >> 13;
      unsigned r2   = r & 8191u;
      unsigned l    = r2 >> 12;
      unsigned r3   = r2 & 4095u;
      unsigned kt   = r3 >> 9;
      unsigned r4   = r3 & 511u;
      unsigned lane = r4 >> 3;
      unsigned e    = r4 & 7u;
      unsigned n = lane & 15u, q = lane >> 4;
      unsigned g = n >> 2, jj = n & 3u;
      unsigned col = (g << 10) + (wg << 2) + jj;
      unsigned kloc = (wv << 7) + ((kt & 3u) << 5) + (q << 3) + e;
      float v = (kt < 4u) ? whh[(l << 22) + (col << 10) + kloc]
                          : wih[(l << 22) + (col << 10) + kloc];
      wreg[idx] = pack_split(v);
    } else if (idx < 17825792u) {            // wfc separated [1024][512 hi|512 lo]
      unsigned i2 = idx - 16777216u;
      unsigned r = i2 >> 10, j = i2 & 1023u;
      const float* src = wfc_in + (r << 10) + ((j & 511u) << 1);
      unsigned short h0 = f2bf(src[0]);
      unsigned short h1 = f2bf(src[1]);
      unsigned dwv;
      if (j < 512u) {
        dwv = (unsigned)h0 | ((unsigned)h1 << 16);
      } else {
        unsigned short l0 = f2bf(src[0] - bf2f(h0));
        unsigned short l1 = f2bf(src[1] - bf2f(h1));
        dwv = (unsigned)l0 | ((unsigned)l1 << 16);
      }
      wfc[i2] = dwv;
    } else if (idx < 17891328u) {            // xinit separated [64][512 hi|512 lo]
      unsigned i3 = idx - 17825792u;
      unsigned r = i3 >> 10, j = i3 & 1023u;
      const float* src = hin + (r << 10) + ((j & 511u) << 1);
      unsigned short h0 = f2bf(src[0]);
      unsigned short h1 = f2bf(src[1]);
      unsigned dwv;
      if (j < 512u) {
        dwv = (unsigned)h0 | ((unsigned)h1 << 16);
      } else {
        unsigned short l0 = f2bf(src[0] - bf2f(h0));
        unsigned short l1 = f2bf(src[1] - bf2f(h1));
        dwv = (unsigned)l0 | ((unsigned)l1 << 16);
      }
      xinit[i3] = dwv;
    }
  }
}

// ---------- generic grid barrier (initial use only; __syncthreads OK here) ----------
__device__ __forceinline__ void grid_barrier(unsigned* barp, unsigned g,
                                             int wid, int tid) {
  __syncthreads();
  if (wid == 0) {
    if (tid > 0 && tid < NBLK) {
      while (__hip_atomic_load(&barp[512 + tid], __ATOMIC_RELAXED,
                               __HIP_MEMORY_SCOPE_AGENT) < g) {
        __builtin_amdgcn_s_sleep(1);
      }
    }
    __syncthreads();
    if (tid < 8) {
      __hip_atomic_store(&barp[tid << 5], g, __ATOMIC_RELAXED, __HIP_MEMORY_SCOPE_AGENT);
    }
  } else {
    if (tid == 0) {
      __hip_atomic_store(&barp[512 + wid], g, __ATOMIC_RELAXED, __HIP_MEMORY_SCOPE_AGENT);
      while (__hip_atomic_load(&barp[(wid & 7) << 5], __ATOMIC_RELAXED,
                               __HIP_MEMORY_SCOPE_AGENT) < g) {
        __builtin_amdgcn_s_sleep(2);
      }
    }
  }
  __syncthreads();
}

// ---------- main persistent LSTM ----------
// A-fragments loaded DIRECTLY global->VGPR (no LDS staging): 2-slot register ring,
// counted vmcnt. Slabs hi/lo-separated so a 16B load is a ready bf16x8 fragment
// (zero unpack VALU in the hot loop). Phase-tail uses raw s_barrier + explicit
// counted waitcnts so the 16-load hs prologue truly stays in flight across the
// grid barrier (r1's __syncthreads drained vmcnt(0) and killed the overlap).
__global__ __launch_bounds__(512, 1) void lstm_main(
    const unsigned* __restrict__ wreg,
    unsigned* __restrict__ h0buf,      // [128][64][1024] separated (aliases wreg low half)
    const unsigned* __restrict__ xinit,
    const unsigned* __restrict__ hzero,
    unsigned* __restrict__ rec,        // [128][64][1024] separated
    const float* __restrict__ bih, const float* __restrict__ bhh,
    unsigned* __restrict__ barp) {
  __shared__ float part[8 * 2304];  // 73728 B: per-wave 64 rows x 36 (stride-36, conflict-free)

  const int tid = threadIdx.x;
  const int wid = blockIdx.x;
  const int wave = tid >> 6;
  const int lane = tid & 63;
  const int q = lane >> 4;
  const int m16 = lane & 15;

  // ---- weight slice -> registers, pin ----
  bf16x8 whi[2][8], wlo[2][8];
  {
    const unsigned* wb = wreg + ((size_t)wid << 16) + ((size_t)wave << 13) + (lane << 3);
    #pragma unroll
    for (int l = 0; l < 2; ++l)
      #pragma unroll
      for (int kt = 0; kt < 8; ++kt) {
        const unsigned* p = wb + (l << 12) + (kt << 9);
        uint4 a0 = *(const uint4*)p;
        uint4 a1 = *(const uint4*)(p + 4);
        unpack2(a0, a1, whi[l][kt], wlo[l][kt]);
      }
    #pragma unroll
    for (int l = 0; l < 2; ++l)
      #pragma unroll
      for (int kt = 0; kt < 8; ++kt) {
        asm volatile("" : "+v"(whi[l][kt]), "+v"(wlo[l][kt]));
      }
  }

  // EW thread state (threads 0..255 own (b=tid>>2, jj=tid&3))
  const int eb = tid >> 2;
  const int ej = tid & 3;
  float creg[2] = {0.0f, 0.0f};
  float biasr[2][4] = {{0, 0, 0, 0}, {0, 0, 0, 0}};
  if (tid < 256) {
    #pragma unroll
    for (int l = 0; l < 2; ++l)
      #pragma unroll
      for (int g = 0; g < 4; ++g) {
        int col = (g << 10) + (wid << 2) + ej;
        biasr[l][g] = bih[(l << 12) + col] + bhh[(l << 12) + col];
      }
  }

  grid_barrier(barp, 1u, wid, tid);
  __builtin_amdgcn_fence(__ATOMIC_ACQUIRE, "agent");

  // phase-invariant per-lane byte offsets: row = mt*16+m16; +wave k-slice; +q slot
  unsigned voff[4];
  #pragma unroll
  for (int mt = 0; mt < 4; ++mt)
    voff[mt] = (unsigned)(((mt << 4) + m16) << 12) + (unsigned)(wave << 8) + (unsigned)(q << 4);

  uint4 fh[2][4], fl[2][4];  // 2-slot fragment ring (static indices only)

  #define LOADC(slot_, srcb_, ktl_)                                          \
    { _Pragma("unroll")                                                      \
      for (int mt = 0; mt < 4; ++mt) {                                       \
        const char* pb = (const char*)(srcb_) + voff[mt] + ((ktl_) << 6);    \
        fh[slot_][mt] = *(const uint4*)pb;                                   \
        fl[slot_][mt] = *(const uint4*)(pb + 2048);                          \
      } }

  const float* pbase = part;
  float* wpart = part + wave * 2304;
  const int pcol = ((m16 & 3) << 2) | (m16 >> 2);  // perm so reduce reads are b128
  const f32x4 fzero = {0.0f, 0.0f, 0.0f, 0.0f};

  // initial prologue: phase (0,0) hs = hzero, chunks 0,1
  LOADC(0, hzero, 0)
  LOADC(1, hzero, 1)

  for (int t = 0; t < 128; ++t) {
    #pragma unroll
    for (int l = 0; l < 2; ++l) {
      const unsigned* xs;
      const unsigned* hsv;
      unsigned* dst;
      if (l == 0) {
        xs  = (t == 0) ? xinit : rec + ((t - 1) << 16);
        hsv = (t == 0) ? hzero : h0buf + ((t - 1) << 16);
        dst = h0buf + (t << 16);
      } else {
        xs  = h0buf + (t << 16);
        hsv = (t == 0) ? hzero : rec + ((t - 1) << 16);
        dst = rec + (t << 16);
      }

      f32x4 acc[4];
      #pragma unroll
      for (int mt = 0; mt < 4; ++mt) acc[mt] = fzero;

      // chunks 0-3 = hs (W_hh), 4-7 = xs (W_ih); 0,1 already in flight
      #pragma unroll
      for (int kt = 0; kt < 8; ++kt) {
        if (kt < 7) {
          asm volatile("s_waitcnt vmcnt(8)" ::: "memory");
        } else {
          asm volatile("s_waitcnt vmcnt(0)" ::: "memory");
        }
        const int slot = kt & 1;
        #pragma unroll
        for (int mt = 0; mt < 4; ++mt) {
          bf16x8 ahi = as_bf(fh[slot][mt]);
          bf16x8 alo = as_bf(fl[slot][mt]);
          acc[mt] = __builtin_amdgcn_mfma_f32_16x16x32_bf16(ahi, whi[l][kt], acc[mt], 0, 0, 0);
          acc[mt] = __builtin_amdgcn_mfma_f32_16x16x32_bf16(ahi, wlo[l][kt], acc[mt], 0, 0, 0);
          acc[mt] = __builtin_amdgcn_mfma_f32_16x16x32_bf16(alo, whi[l][kt], acc[mt], 0, 0, 0);
        }
        // issue chunk kt+2 into the slot just consumed
        if (kt == 0)      LOADC(0, hsv, 2)
        else if (kt == 1) LOADC(1, hsv, 3)
        else if (kt == 2) LOADC(0, xs, 0)
        else if (kt == 3) LOADC(1, xs, 1)
        else if (kt == 4) LOADC(0, xs, 2)
        else if (kt == 5) LOADC(1, xs, 3)
      }

      // partials -> own wave region (stride 36, perm'd cols)
      #pragma unroll
      for (int mt = 0; mt < 4; ++mt)
        #pragma unroll
        for (int r = 0; r < 4; ++r) {
          int m = (mt << 4) + (q << 2) + r;
          wpart[m * 36 + pcol] = acc[mt][r];
        }
      __syncthreads();   // A1: vm outstanding==0 here, lgkm drain is needed anyway

      if (tid < 256) {
        f32x4 s4 = {biasr[l][0], biasr[l][1], biasr[l][2], biasr[l][3]};
        #pragma unroll
        for (int w = 0; w < 8; ++w) {
          const f32x4 pv = *(const f32x4*)&pbase[w * 2304 + eb * 36 + (ej << 2)];
          s4 += pv;
        }
        float ig = sigm(s4.x);
        float fg = sigm(s4.y);
        float gv = tanh_f(s4.z);
        float og = sigm(s4.w);
        float cn = fg * creg[l] + ig * gv;
        float hn = og * tanh_f(cn);
        creg[l] = cn;
        unsigned hiv = f2bf(hn);
        unsigned lov = f2bf(hn - bf2f((unsigned short)hiv));
        unsigned phi = __shfl_xor(hiv, 1);
        unsigned plo = __shfl_xor(lov, 1);
        unsigned dw = (ej & 1) ? (plo | (lov << 16)) : (hiv | (phi << 16));
        int idx = (eb << 10) + ((ej & 1) << 9) + (wid << 1) + (ej >> 1);
        __hip_atomic_store(&dst[idx], dw, __ATOMIC_RELAXED, __HIP_MEMORY_SCOPE_AGENT);
      }

      if (t == 127 && l == 1) return;   // kernel end publishes + orders before fc

      // prologue: next phase hs chunks 0,1 (data already globally visible)
      {
        const unsigned* nh = (l == 0)
            ? ((t == 0) ? hzero : rec + ((t - 1) << 16))
            : (h0buf + (t << 16));
        LOADC(0, nh, 0)
        LOADC(1, nh, 1)
      }

      // EW stores (older than the 16 prologue loads) drained by counting:
      if (tid < 256) {
        asm volatile("s_waitcnt vmcnt(16)" ::: "memory");
      }
      asm volatile("" ::: "memory");
      __builtin_amdgcn_s_barrier();      // A2 (raw: prologue stays in flight)
      asm volatile("" ::: "memory");

      {
        const unsigned g = (unsigned)(2 * t + l + 2);
        if (wid == 0) {
          if (tid > 0 && tid < NBLK) {
            while (__hip_atomic_load(&barp[512 + tid], __ATOMIC_RELAXED,
                                     __HIP_MEMORY_SCOPE_AGENT) < g) {
              __builtin_amdgcn_s_sleep(1);
            }
          }
          asm volatile("" ::: "memory");
          __builtin_amdgcn_s_barrier();
          asm volatile("" ::: "memory");
          if (tid < 8) {
            __hip_atomic_store(&barp[tid << 5], g, __ATOMIC_RELAXED,
                               __HIP_MEMORY_SCOPE_AGENT);
          }
        } else {
          if (tid == 0) {
            __hip_atomic_store(&barp[512 + wid], g, __ATOMIC_RELAXED,
                               __HIP_MEMORY_SCOPE_AGENT);
            while (__hip_atomic_load(&barp[(wid & 7) << 5], __ATOMIC_RELAXED,
                                     __HIP_MEMORY_SCOPE_AGENT) < g) {
              __builtin_amdgcn_s_sleep(2);
            }
          }
        }
      }
      asm volatile("" ::: "memory");
      __builtin_amdgcn_s_barrier();      // B (raw: release; prologue still in flight)
      asm volatile("" ::: "memory");
    }
  }
  #undef LOADC
}

// ---------- FC: out[8192,1024] = rec @ Wfc^T + b_fc (separated hi/lo layout) ----------
__global__ __launch_bounds__(256) void fc_kernel(
    const unsigned* __restrict__ rec, const unsigned* __restrict__ wfc,
    const float* __restrict__ bfc, float* __restrict__ out) {
  __shared__ unsigned a_lds[128 * 36];
  __shared__ unsigned w_lds[128 * 36];
  const int tid = threadIdx.x;
  const int wave = tid >> 6;
  const int lane = tid & 63;
  const int q = lane >> 4;
  const int m16 = lane & 15;
  const int m0 = (blockIdx.x >> 3) << 7;
  const int n0 = (blockIdx.x & 7) << 7;
  const f32x4 fzero = {0.0f, 0.0f, 0.0f, 0.0f};

  f32x4 acc[2][8];
  for (int mt = 0; mt < 2; ++mt)
    for (int nt = 0; nt < 8; ++nt) acc[mt][nt] = fzero;

  for (int kc = 0; kc < 32; ++kc) {
    __syncthreads();
    #pragma unroll
    for (int i = 0; i < 4; ++i) {
      int c = (i << 8) + tid;
      int r = c >> 3;
      int cc = (c & 7) << 2;
      int gsrc = (cc < 16) ? ((kc << 4) + cc) : (512 + (kc << 4) + cc - 16);
      *(uint4*)(a_lds + r * 36 + cc) = *(const uint4*)(rec + ((m0 + r) << 10) + gsrc);
      *(uint4*)(w_lds + r * 36 + cc) = *(const uint4*)(wfc + ((n0 + r) << 10) + gsrc);
    }
    __syncthreads();

    bf16x8 ahi[2], alo[2];
    #pragma unroll
    for (int mt = 0; mt < 2; ++mt) {
      int arow = (wave << 5) + (mt << 4) + m16;
      ahi[mt] = as_bf(*(const uint4*)(a_lds + arow * 36 + (q << 2)));
      alo[mt] = as_bf(*(const uint4*)(a_lds + arow * 36 + 16 + (q << 2)));
    }
    #pragma unroll
    for (int nt = 0; nt < 8; ++nt) {
      int wrow = (nt << 4) + m16;
      bf16x8 bhi = as_bf(*(const uint4*)(w_lds + wrow * 36 + (q << 2)));
      bf16x8 blo = as_bf(*(const uint4*)(w_lds + wrow * 36 + 16 + (q << 2)));
      #pragma unroll
      for (int mt = 0; mt < 2; ++mt) {
        acc[mt][nt] = __builtin_amdgcn_mfma_f32_16x16x32_bf16(ahi[mt], bhi, acc[mt][nt], 0, 0, 0);
        acc[mt][nt] = __builtin_amdgcn_mfma_f32_16x16x32_bf16(ahi[mt], blo, acc[mt][nt], 0, 0, 0);
        acc[mt][nt] = __builtin_amdgcn_mfma_f32_16x16x32_bf16(alo[mt], bhi, acc[mt][nt], 0, 0, 0);
      }
    }
  }
  #pragma unroll
  for (int mt = 0; mt < 2; ++mt)
    #pragma unroll
    for (int nt = 0; nt < 8; ++nt) {
      int n = n0 + (nt << 4) + m16;
      float bv = bfc[n];
      #pragma unroll
      for (int r2 = 0; r2 < 4; ++r2) {
        int m = m0 + (wave << 5) + (mt << 4) + (q << 2) + r2;
        out[(m << 10) + n] = acc[mt][nt][r2] + bv;
      }
    }
}

// ---------- launch ----------
extern "C" void kernel_launch(void* const* d_in, const int* in_sizes, int n_in,
                              void* d_out, int out_size, void* d_ws, size_t ws_size,
                              hipStream_t stream) {
  const float* h_in = (const float*)d_in[0];
  const float* W_ih = (const float*)d_in[1];
  const float* W_hh = (const float*)d_in[2];
  const float* b_ih = (const float*)d_in[3];
  const float* b_hh = (const float*)d_in[4];
  const float* W_fc = (const float*)d_in[5];
  const float* b_fc = (const float*)d_in[6];
  (void)in_sizes; (void)n_in; (void)out_size; (void)ws_size;

  char* ws = (char*)d_ws;
  unsigned* wreg  = (unsigned*)(ws + 0);          // 64 MB
  unsigned* h0buf = (unsigned*)(ws + 0);          // 32 MB, aliases wreg lower half
  unsigned* wfc   = (unsigned*)(ws + 67108864);   // 4 MB (separated)
  unsigned* xinit = (unsigned*)(ws + 71303168);   // 256 KB (separated)
  unsigned* hzero = (unsigned*)(ws + 71565312);   // 256 KB zeros
  unsigned* barp  = (unsigned*)(ws + 71827456);   // [j<<5]=gen copies, [512+wid]=flags
  unsigned* rec   = (unsigned*)(ws + 72616192);   // 32 MB (separated)
  float*    out   = (float*)d_out;

  (void)hipMemsetAsync(ws + 71565312, 0, 262144 + 266240, stream);

  prep_kernel<<<dim3(8736), dim3(256), 0, stream>>>(W_ih, W_hh, W_fc, h_in,
                                                    wreg, wfc, xinit);

  lstm_main<<<dim3(NBLK), dim3(512), 0, stream>>>(wreg, h0buf, xinit, hzero, rec,
                                                  b_ih, b_hh, barp);

  fc_kernel<<<dim3(512), dim3(256), 0, stream>>>(rec, wfc, b_fc, out);
}

// Round 3
// 2432.362 us; speedup vs baseline: 1.6926x; 1.6926x over previous
//
#include <hip/hip_runtime.h>

typedef __attribute__((ext_vector_type(8))) short bf16x8;
typedef __attribute__((ext_vector_type(4))) float f32x4;

#define NBLK 256

typedef __attribute__((address_space(3))) unsigned lds_u;
typedef __attribute__((address_space(1))) const unsigned glb_u;

// ---------- helpers ----------
__device__ __forceinline__ unsigned short f2bf(float f) {
  unsigned u = __float_as_uint(f);
  unsigned r = u + 0x7fffu + ((u >> 16) & 1u);   // RNE
  return (unsigned short)(r >> 16);
}
__device__ __forceinline__ float bf2f(unsigned short h) {
  return __uint_as_float(((unsigned)h) << 16);
}
__device__ __forceinline__ unsigned pack_split(float f) {
  unsigned short hi = f2bf(f);
  float res = f - bf2f(hi);
  unsigned short lo = f2bf(res);
  return (((unsigned)hi) << 16) | (unsigned)lo;
}
// 8 packed weight dwords (2x uint4) -> hi-frag / lo-frag (weight reg-load only)
__device__ __forceinline__ void unpack2(uint4 a0, uint4 a1, bf16x8& hi, bf16x8& lo) {
  union { bf16x8 v; unsigned u[4]; } H, L;
  H.u[0] = (a0.x >> 16) | (a0.y & 0xffff0000u);
  L.u[0] = (a0.x & 0xffffu) | (a0.y << 16);
  H.u[1] = (a0.z >> 16) | (a0.w & 0xffff0000u);
  L.u[1] = (a0.z & 0xffffu) | (a0.w << 16);
  H.u[2] = (a1.x >> 16) | (a1.y & 0xffff0000u);
  L.u[2] = (a1.x & 0xffffu) | (a1.y << 16);
  H.u[3] = (a1.z >> 16) | (a1.w & 0xffff0000u);
  L.u[3] = (a1.z & 0xffffu) | (a1.w << 16);
  hi = H.v; lo = L.v;
}
union U4B { uint4 u; bf16x8 b; };
__device__ __forceinline__ bf16x8 as_bf(uint4 u) { U4B x; x.u = u; return x.b; }
__device__ __forceinline__ float sigm(float x) { return 1.0f / (1.0f + __expf(-x)); }
__device__ __forceinline__ float tanh_f(float x) { return 1.0f - 2.0f / (__expf(2.0f * x) + 1.0f); }

// ---------- prep ----------
// Weights (r2 mapping, verified): wreg[wg][wave][l][kt][lane][e] packed dwords;
// kloc = wv*128 + (kt&3)*32 + q*8 + e ; kt<4 -> W_hh, else W_ih.
// Activation slabs INTERLEAVED-PER-CHUNK: [row][kc=32][16 hi-dw | 16 lo-dw];
// dword kc*32 + p      = hi(c0)|hi(c1)<<16,  c0 = kc*32 + 2p
// dword kc*32 + 16 + p = lo(c0)|lo(c1)<<16
__global__ __launch_bounds__(256) void prep_kernel(
    const float* __restrict__ wih, const float* __restrict__ whh,
    const float* __restrict__ wfc_in, const float* __restrict__ hin,
    unsigned* __restrict__ wreg, unsigned* __restrict__ wfc, unsigned* __restrict__ xinit) {
  for (int e0 = 0; e0 < 8; ++e0) {
    unsigned idx = blockIdx.x * 2048u + (unsigned)e0 * 256u + threadIdx.x;
    if (idx < 16777216u) {
      unsigned wg   = idx >> 16;
      unsigned r    = idx & 65535u;
      unsigned wv   = r >> 13;
      unsigned r2   = r & 8191u;
      unsigned l    = r2 >> 12;
      unsigned r3   = r2 & 4095u;
      unsigned kt   = r3 >> 9;
      unsigned r4   = r3 & 511u;
      unsigned lane = r4 >> 3;
      unsigned e    = r4 & 7u;
      unsigned n = lane & 15u, q = lane >> 4;
      unsigned g = n >> 2, jj = n & 3u;
      unsigned col = (g << 10) + (wg << 2) + jj;
      unsigned kloc = (wv << 7) + ((kt & 3u) << 5) + (q << 3) + e;
      float v = (kt < 4u) ? whh[(l << 22) + (col << 10) + kloc]
                          : wih[(l << 22) + (col << 10) + kloc];
      wreg[idx] = pack_split(v);
    } else if (idx < 17825792u) {            // wfc interleaved-per-chunk
      unsigned i2 = idx - 16777216u;
      unsigned r = i2 >> 10, d = i2 & 1023u;
      unsigned kc = d >> 5, rest = d & 31u;
      unsigned half = rest >> 4, p = rest & 15u;
      const float* src = wfc_in + (r << 10) + (kc << 5) + (p << 1);
      unsigned short h0 = f2bf(src[0]);
      unsigned short h1 = f2bf(src[1]);
      unsigned dwv;
      if (half == 0u) {
        dwv = (unsigned)h0 | ((unsigned)h1 << 16);
      } else {
        unsigned short l0 = f2bf(src[0] - bf2f(h0));
        unsigned short l1 = f2bf(src[1] - bf2f(h1));
        dwv = (unsigned)l0 | ((unsigned)l1 << 16);
      }
      wfc[i2] = dwv;
    } else if (idx < 17891328u) {            // xinit interleaved-per-chunk
      unsigned i3 = idx - 17825792u;
      unsigned r = i3 >> 10, d = i3 & 1023u;
      unsigned kc = d >> 5, rest = d & 31u;
      unsigned half = rest >> 4, p = rest & 15u;
      const float* src = hin + (r << 10) + (kc << 5) + (p << 1);
      unsigned short h0 = f2bf(src[0]);
      unsigned short h1 = f2bf(src[1]);
      unsigned dwv;
      if (half == 0u) {
        dwv = (unsigned)h0 | ((unsigned)h1 << 16);
      } else {
        unsigned short l0 = f2bf(src[0] - bf2f(h0));
        unsigned short l1 = f2bf(src[1] - bf2f(h1));
        dwv = (unsigned)l0 | ((unsigned)l1 << 16);
      }
      xinit[i3] = dwv;
    }
  }
}

// ---------- generic grid barrier (initial use only) ----------
__device__ __forceinline__ void grid_barrier(unsigned* barp, unsigned g,
                                             int wid, int tid) {
  __syncthreads();
  if (wid == 0) {
    if (tid > 0 && tid < NBLK) {
      while (__hip_atomic_load(&barp[512 + tid], __ATOMIC_RELAXED,
                               __HIP_MEMORY_SCOPE_AGENT) < g) {
        __builtin_amdgcn_s_sleep(1);
      }
    }
    __syncthreads();
    if (tid < 8) {
      __hip_atomic_store(&barp[tid << 5], g, __ATOMIC_RELAXED, __HIP_MEMORY_SCOPE_AGENT);
    }
  } else {
    if (tid == 0) {
      __hip_atomic_store(&barp[512 + wid], g, __ATOMIC_RELAXED, __HIP_MEMORY_SCOPE_AGENT);
      while (__hip_atomic_load(&barp[(wid & 7) << 5], __ATOMIC_RELAXED,
                               __HIP_MEMORY_SCOPE_AGENT) < g) {
        __builtin_amdgcn_s_sleep(2);
      }
    }
  }
  __syncthreads();
}

// ---------- main persistent LSTM ----------
// global_load_lds staging (r1 structure, proven coalescing: 8x128B per instr)
// + interleaved-per-chunk slabs (LDS b128 read == ready fragment, no unpack)
// + XOR-swizzled slots (2-way max conflicts) + raw-s_barrier tail with counted
// vmcnt so next-phase hs chunks 0,1 stay in flight across the grid barrier.
__global__ __launch_bounds__(512, 1) void lstm_main(
    const unsigned* __restrict__ wreg,
    unsigned* __restrict__ h0buf,      // [128][64][1024] (aliases wreg low half)
    const unsigned* __restrict__ xinit,
    const unsigned* __restrict__ hzero,
    unsigned* __restrict__ rec,        // [128][64][1024]
    const float* __restrict__ bih, const float* __restrict__ bhh,
    unsigned* __restrict__ barp) {
  __shared__ unsigned stage_lds[8][2][2048];  // 128 KB: wave x dbuf x 8KB chunk
  __shared__ float part_lds[8][64][16];       // 32 KB partials

  const int tid = threadIdx.x;
  const int wid = blockIdx.x;
  const int wave = tid >> 6;
  const int lane = tid & 63;
  const int q = lane >> 4;
  const int m16 = lane & 15;

  // ---- weight slice -> registers, pin ----
  bf16x8 whi[2][8], wlo[2][8];
  {
    const unsigned* wb = wreg + ((size_t)wid << 16) + ((size_t)wave << 13) + (lane << 3);
    #pragma unroll
    for (int l = 0; l < 2; ++l)
      #pragma unroll
      for (int kt = 0; kt < 8; ++kt) {
        const unsigned* p = wb + (l << 12) + (kt << 9);
        uint4 a0 = *(const uint4*)p;
        uint4 a1 = *(const uint4*)(p + 4);
        unpack2(a0, a1, whi[l][kt], wlo[l][kt]);
      }
    #pragma unroll
    for (int l = 0; l < 2; ++l)
      #pragma unroll
      for (int kt = 0; kt < 8; ++kt) {
        asm volatile("" : "+v"(whi[l][kt]), "+v"(wlo[l][kt]));
      }
  }

  // EW thread state (threads 0..255 own (b=tid>>2, jj=tid&3))
  const int eb = tid >> 2;
  const int ej = tid & 3;
  float creg[2] = {0.0f, 0.0f};
  float biasr[2][4] = {{0, 0, 0, 0}, {0, 0, 0, 0}};
  if (tid < 256) {
    #pragma unroll
    for (int l = 0; l < 2; ++l)
      #pragma unroll
      for (int g = 0; g < 4; ++g) {
        int col = (g << 10) + (wid << 2) + ej;
        biasr[l][g] = bih[(l << 12) + col] + bhh[(l << 12) + col];
      }
  }

  grid_barrier(barp, 1u, wid, tid);
  __builtin_amdgcn_fence(__ATOMIC_ACQUIRE, "agent");

  unsigned* const myst = &stage_lds[wave][0][0];
  const int kcgh = wave << 2;          // wave's first chunk index (of 32)
  const f32x4 fzero = {0.0f, 0.0f, 0.0f, 0.0f};

  // staging-issue lane geometry: instr i covers rows r=i*8+st_r, swizzled slot
  const int st_r  = lane >> 3;
  const int st_cs = lane & 7;
  const int pcol = ((m16 & 3) << 2) | (m16 >> 2);  // partials col perm (b128 reduce)

  // chunk kcg of slab srcp_ -> buf bsel_ (linear dest, pre-swizzled source)
  #define ISSUE(bsel_, srcp_, kcg_)                                                \
    {                                                                              \
      _Pragma("unroll")                                                            \
      for (int i = 0; i < 8; ++i) {                                                \
        int r = (i << 3) + st_r;                                                   \
        int c = st_cs ^ (r & 7);                                                   \
        const unsigned* gp = (srcp_) + (r << 10) + ((kcg_) << 5) + (c << 2);       \
        unsigned* lp = myst + ((bsel_) << 11) + (i << 8);                          \
        __builtin_amdgcn_global_load_lds((glb_u*)gp, (lds_u*)lp, 16, 0, 0);        \
      }                                                                            \
    }

  // initial prologue: phase (0,0) hs = hzero, chunks 0,1
  ISSUE(0, hzero, kcgh)
  ISSUE(1, hzero, kcgh + 1)

  for (int t = 0; t < 128; ++t) {
    #pragma unroll
    for (int l = 0; l < 2; ++l) {
      const unsigned* srcx;
      const unsigned* srch;
      unsigned* dst;
      if (l == 0) {
        srcx = (t == 0) ? xinit : rec + ((t - 1) << 16);
        srch = (t == 0) ? hzero : h0buf + ((t - 1) << 16);
        dst = h0buf + (t << 16);
      } else {
        srcx = h0buf + (t << 16);
        srch = (t == 0) ? hzero : rec + ((t - 1) << 16);
        dst = rec + (t << 16);
      }
      const bool last = (t == 127) && (l == 1);
      // next phase's hs slab (published >=1 barrier ago -> safe to prefetch)
      const unsigned* nh = (l == 0)
          ? ((t == 0) ? hzero : rec + ((t - 1) << 16))
          : (h0buf + (t << 16));

      f32x4 acc[4];
      #pragma unroll
      for (int mt = 0; mt < 4; ++mt) acc[mt] = fzero;

      // chunks 0-3 = hs (W_hh), 4-7 = xs (W_ih); chunks 0,1 already in flight
      #pragma unroll
      for (int kt = 0; kt < 8; ++kt) {
        if (kt < 7) {
          asm volatile("s_waitcnt vmcnt(8)" ::: "memory");
        } else {
          asm volatile("s_waitcnt vmcnt(0)" ::: "memory");
        }
        const int bsel = kt & 1;
        const unsigned* bufb = myst + (bsel << 11);
        bf16x8 ahi[4], alo[4];
        #pragma unroll
        for (int mt = 0; mt < 4; ++mt) {
          int row = (mt << 4) + m16;
          const unsigned* rb = bufb + (row << 5);
          ahi[mt] = as_bf(*(const uint4*)(rb + ((q ^ (m16 & 7)) << 2)));
          alo[mt] = as_bf(*(const uint4*)(rb + (((4 | q) ^ (m16 & 7)) << 2)));
        }
        asm volatile("s_waitcnt lgkmcnt(0)" ::: "memory");
        if (kt == 0)      ISSUE(0, srch, kcgh + 2)
        else if (kt == 1) ISSUE(1, srch, kcgh + 3)
        else if (kt == 2) ISSUE(0, srcx, kcgh + 0)
        else if (kt == 3) ISSUE(1, srcx, kcgh + 1)
        else if (kt == 4) ISSUE(0, srcx, kcgh + 2)
        else if (kt == 5) ISSUE(1, srcx, kcgh + 3)
        else if (kt == 7 && wave >= 4 && !last) {
          ISSUE(0, nh, kcgh)
          ISSUE(1, nh, kcgh + 1)
        }
        #pragma unroll
        for (int mt = 0; mt < 4; ++mt) {
          bf16x8 ah = ahi[mt], al = alo[mt];
          acc[mt] = __builtin_amdgcn_mfma_f32_16x16x32_bf16(ah, whi[l][kt], acc[mt], 0, 0, 0);
          acc[mt] = __builtin_amdgcn_mfma_f32_16x16x32_bf16(ah, wlo[l][kt], acc[mt], 0, 0, 0);
          acc[mt] = __builtin_amdgcn_mfma_f32_16x16x32_bf16(al, whi[l][kt], acc[mt], 0, 0, 0);
        }
      }

      // partials -> dedicated region
      #pragma unroll
      for (int mt = 0; mt < 4; ++mt)
        #pragma unroll
        for (int r = 0; r < 4; ++r) {
          int m = (mt << 4) + (q << 2) + r;
          part_lds[wave][m][pcol] = acc[mt][r];
        }
      asm volatile("s_waitcnt lgkmcnt(0)" ::: "memory");
      __builtin_amdgcn_s_barrier();      // A1: partials visible (vm stays in flight)
      asm volatile("" ::: "memory");

      if (tid < 256) {
        f32x4 s4 = {biasr[l][0], biasr[l][1], biasr[l][2], biasr[l][3]};
        #pragma unroll
        for (int w = 0; w < 8; ++w) {
          s4 += *(const f32x4*)&part_lds[w][eb][ej << 2];
        }
        float ig = sigm(s4.x);
        float fg = sigm(s4.y);
        float gv = tanh_f(s4.z);
        float og = sigm(s4.w);
        float cn = fg * creg[l] + ig * gv;
        float hn = og * tanh_f(cn);
        creg[l] = cn;
        unsigned hiv = f2bf(hn);
        unsigned lov = f2bf(hn - bf2f((unsigned short)hiv));
        unsigned phi = __shfl_xor(hiv, 1);
        unsigned plo = __shfl_xor(lov, 1);
        unsigned dw = (ej & 1) ? (plo | (lov << 16)) : (hiv | (phi << 16));
        int idx = (eb << 10) + ((wid >> 3) << 5) + ((ej & 1) << 4) +
                  ((wid & 7) << 1) + (ej >> 1);
        __hip_atomic_store(&dst[idx], dw, __ATOMIC_RELAXED, __HIP_MEMORY_SCOPE_AGENT);
        asm volatile("" ::: "memory");   // pin store before prologue loads
        if (!last) {
          ISSUE(0, nh, kcgh)
          ISSUE(1, nh, kcgh + 1)
          // 16 newer loads outstanding -> the older publish store has retired
          asm volatile("s_waitcnt vmcnt(16)" ::: "memory");
        }
      }
      if (last) return;

      asm volatile("" ::: "memory");
      __builtin_amdgcn_s_barrier();      // A2: all publishes drained
      asm volatile("" ::: "memory");
      {
        const unsigned g = (unsigned)(2 * t + l + 2);
        if (wid == 0) {
          if (tid > 0 && tid < NBLK) {
            while (__hip_atomic_load(&barp[512 + tid], __ATOMIC_RELAXED,
                                     __HIP_MEMORY_SCOPE_AGENT) < g) {
              __builtin_amdgcn_s_sleep(1);
            }
          }
          asm volatile("" ::: "memory");
          __builtin_amdgcn_s_barrier();
          asm volatile("" ::: "memory");
          if (tid < 8) {
            __hip_atomic_store(&barp[tid << 5], g, __ATOMIC_RELAXED,
                               __HIP_MEMORY_SCOPE_AGENT);
          }
        } else {
          if (tid == 0) {
            __hip_atomic_store(&barp[512 + wid], g, __ATOMIC_RELAXED,
                               __HIP_MEMORY_SCOPE_AGENT);
            while (__hip_atomic_load(&barp[(wid & 7) << 5], __ATOMIC_RELAXED,
                                     __HIP_MEMORY_SCOPE_AGENT) < g) {
              __builtin_amdgcn_s_sleep(2);
            }
          }
        }
      }
      asm volatile("" ::: "memory");
      __builtin_amdgcn_s_barrier();      // B: release (hs prologue still in flight)
      asm volatile("" ::: "memory");
    }
  }
  #undef ISSUE
}

// ---------- FC: out[8192,1024] = rec @ Wfc^T + b_fc (interleaved layout) ----------
__global__ __launch_bounds__(256) void fc_kernel(
    const unsigned* __restrict__ rec, const unsigned* __restrict__ wfc,
    const float* __restrict__ bfc, float* __restrict__ out) {
  __shared__ unsigned a_lds[128 * 36];
  __shared__ unsigned w_lds[128 * 36];
  const int tid = threadIdx.x;
  const int wave = tid >> 6;
  const int lane = tid & 63;
  const int q = lane >> 4;
  const int m16 = lane & 15;
  const int m0 = (blockIdx.x >> 3) << 7;
  const int n0 = (blockIdx.x & 7) << 7;
  const f32x4 fzero = {0.0f, 0.0f, 0.0f, 0.0f};

  f32x4 acc[2][8];
  for (int mt = 0; mt < 2; ++mt)
    for (int nt = 0; nt < 8; ++nt) acc[mt][nt] = fzero;

  for (int kc = 0; kc < 32; ++kc) {
    __syncthreads();
    #pragma unroll
    for (int i = 0; i < 4; ++i) {
      int c = (i << 8) + tid;
      int r = c >> 3;
      int cc = (c & 7) << 2;
      int gsrc = (kc << 5) + cc;   // chunk kc: 32 contiguous dwords (hi16|lo16)
      *(uint4*)(a_lds + r * 36 + cc) = *(const uint4*)(rec + ((m0 + r) << 10) + gsrc);
      *(uint4*)(w_lds + r * 36 + cc) = *(const uint4*)(wfc + ((n0 + r) << 10) + gsrc);
    }
    __syncthreads();

    bf16x8 ahi[2], alo[2];
    #pragma unroll
    for (int mt = 0; mt < 2; ++mt) {
      int arow = (wave << 5) + (mt << 4) + m16;
      ahi[mt] = as_bf(*(const uint4*)(a_lds + arow * 36 + (q << 2)));
      alo[mt] = as_bf(*(const uint4*)(a_lds + arow * 36 + 16 + (q << 2)));
    }
    #pragma unroll
    for (int nt = 0; nt < 8; ++nt) {
      int wrow = (nt << 4) + m16;
      bf16x8 bhi = as_bf(*(const uint4*)(w_lds + wrow * 36 + (q << 2)));
      bf16x8 blo = as_bf(*(const uint4*)(w_lds + wrow * 36 + 16 + (q << 2)));
      #pragma unroll
      for (int mt = 0; mt < 2; ++mt) {
        acc[mt][nt] = __builtin_amdgcn_mfma_f32_16x16x32_bf16(ahi[mt], bhi, acc[mt][nt], 0, 0, 0);
        acc[mt][nt] = __builtin_amdgcn_mfma_f32_16x16x32_bf16(ahi[mt], blo, acc[mt][nt], 0, 0, 0);
        acc[mt][nt] = __builtin_amdgcn_mfma_f32_16x16x32_bf16(alo[mt], bhi, acc[mt][nt], 0, 0, 0);
      }
    }
  }
  #pragma unroll
  for (int mt = 0; mt < 2; ++mt)
    #pragma unroll
    for (int nt = 0; nt < 8; ++nt) {
      int n = n0 + (nt << 4) + m16;
      float bv = bfc[n];
      #pragma unroll
      for (int r2 = 0; r2 < 4; ++r2) {
        int m = m0 + (wave << 5) + (mt << 4) + (q << 2) + r2;
        out[(m << 10) + n] = acc[mt][nt][r2] + bv;
      }
    }
}

// ---------- launch ----------
extern "C" void kernel_launch(void* const* d_in, const int* in_sizes, int n_in,
                              void* d_out, int out_size, void* d_ws, size_t ws_size,
                              hipStream_t stream) {
  const float* h_in = (const float*)d_in[0];
  const float* W_ih = (const float*)d_in[1];
  const float* W_hh = (const float*)d_in[2];
  const float* b_ih = (const float*)d_in[3];
  const float* b_hh = (const float*)d_in[4];
  const float* W_fc = (const float*)d_in[5];
  const float* b_fc = (const float*)d_in[6];
  (void)in_sizes; (void)n_in; (void)out_size; (void)ws_size;

  char* ws = (char*)d_ws;
  unsigned* wreg  = (unsigned*)(ws + 0);          // 64 MB
  unsigned* h0buf = (unsigned*)(ws + 0);          // 32 MB, aliases wreg lower half
  unsigned* wfc   = (unsigned*)(ws + 67108864);   // 4 MB
  unsigned* xinit = (unsigned*)(ws + 71303168);   // 256 KB
  unsigned* hzero = (unsigned*)(ws + 71565312);   // 256 KB zeros
  unsigned* barp  = (unsigned*)(ws + 71827456);   // gens + flags
  unsigned* rec   = (unsigned*)(ws + 72616192);   // 32 MB
  float*    out   = (float*)d_out;

  (void)hipMemsetAsync(ws + 71565312, 0, 262144 + 266240, stream);

  prep_kernel<<<dim3(8736), dim3(256), 0, stream>>>(W_ih, W_hh, W_fc, h_in,
                                                    wreg, wfc, xinit);

  lstm_main<<<dim3(NBLK), dim3(512), 0, stream>>>(wreg, h0buf, xinit, hzero, rec,
                                                  b_ih, b_hh, barp);

  fc_kernel<<<dim3(512), dim3(256), 0, stream>>>(rec, wfc, b_fc, out);
}

// Round 4
// 2254.876 us; speedup vs baseline: 1.8258x; 1.0787x over previous
//
#include <hip/hip_runtime.h>

typedef __attribute__((ext_vector_type(8))) short bf16x8;
typedef __attribute__((ext_vector_type(4))) float f32x4;

#define NBLK 256

// ---------- helpers ----------
__device__ __forceinline__ unsigned short f2bf(float f) {
  unsigned u = __float_as_uint(f);
  unsigned r = u + 0x7fffu + ((u >> 16) & 1u);   // RNE
  return (unsigned short)(r >> 16);
}
__device__ __forceinline__ float bf2f(unsigned short h) {
  return __uint_as_float(((unsigned)h) << 16);
}
__device__ __forceinline__ unsigned pack_split(float f) {
  unsigned short hi = f2bf(f);
  float res = f - bf2f(hi);
  unsigned short lo = f2bf(res);
  return (((unsigned)hi) << 16) | (unsigned)lo;
}
// 8 packed weight dwords (2x uint4) -> hi-frag / lo-frag (weight reg-load only)
__device__ __forceinline__ void unpack2(uint4 a0, uint4 a1, bf16x8& hi, bf16x8& lo) {
  union { bf16x8 v; unsigned u[4]; } H, L;
  H.u[0] = (a0.x >> 16) | (a0.y & 0xffff0000u);
  L.u[0] = (a0.x & 0xffffu) | (a0.y << 16);
  H.u[1] = (a0.z >> 16) | (a0.w & 0xffff0000u);
  L.u[1] = (a0.z & 0xffffu) | (a0.w << 16);
  H.u[2] = (a1.x >> 16) | (a1.y & 0xffff0000u);
  L.u[2] = (a1.x & 0xffffu) | (a1.y << 16);
  H.u[3] = (a1.z >> 16) | (a1.w & 0xffff0000u);
  L.u[3] = (a1.z & 0xffffu) | (a1.w << 16);
  hi = H.v; lo = L.v;
}
union U4B { uint4 u; bf16x8 b; };
__device__ __forceinline__ bf16x8 as_bf(uint4 u) { U4B x; x.u = u; return x.b; }
__device__ __forceinline__ float sigm(float x) { return 1.0f / (1.0f + __expf(-x)); }
__device__ __forceinline__ float tanh_f(float x) { return 1.0f - 2.0f / (__expf(2.0f * x) + 1.0f); }

// ---------- prep ----------
// Weights: wreg[wg][wave][l][kt][lane][e] packed dwords;
//   kloc = wv*128 + (kt&3)*32 + q*8 + e ; kt<4 -> W_hh, else W_ih.
//   Column ownership uses pwid(wg) = ((wg&7)<<5)|(wg>>3) so each XCD's blocks
//   own a contiguous 128-column range (full-line publish combining).
// Activation slabs FRAGMENT-ORDERED (per t, 65536 dwords):
//   dword D = kc*2048 + hl*1024 + mt*256 + lane*4 + ep   (hl: 0=hi,1=lo)
//   holds parts of h[row=mt*16+(lane&15)][col=kc*32+(lane>>4)*8+ep*2 .. +1]
//   => a wave's A-fragment = 64 consecutive 16B lane loads (no LDS needed).
// wfc keeps the interleaved-per-chunk layout [row][kc][16 hi-dw | 16 lo-dw].
__global__ __launch_bounds__(256) void prep_kernel(
    const float* __restrict__ wih, const float* __restrict__ whh,
    const float* __restrict__ wfc_in, const float* __restrict__ hin,
    unsigned* __restrict__ wreg, unsigned* __restrict__ wfc, unsigned* __restrict__ xinit) {
  for (int e0 = 0; e0 < 8; ++e0) {
    unsigned idx = blockIdx.x * 2048u + (unsigned)e0 * 256u + threadIdx.x;
    if (idx < 16777216u) {
      unsigned wg   = idx >> 16;
      unsigned r    = idx & 65535u;
      unsigned wv   = r >> 13;
      unsigned r2   = r & 8191u;
      unsigned l    = r2 >> 12;
      unsigned r3   = r2 & 4095u;
      unsigned kt   = r3 >> 9;
      unsigned r4   = r3 & 511u;
      unsigned lane = r4 >> 3;
      unsigned e    = r4 & 7u;
      unsigned n = lane & 15u, q = lane >> 4;
      unsigned g = n >> 2, jj = n & 3u;
      unsigned col = (g << 10) + ((wg & 7u) << 7) + ((wg >> 3) << 2) + jj;  // pwid*4+jj
      unsigned kloc = (wv << 7) + ((kt & 3u) << 5) + (q << 3) + e;
      float v = (kt < 4u) ? whh[(l << 22) + (col << 10) + kloc]
                          : wih[(l << 22) + (col << 10) + kloc];
      wreg[idx] = pack_split(v);
    } else if (idx < 17825792u) {            // wfc interleaved-per-chunk
      unsigned i2 = idx - 16777216u;
      unsigned r = i2 >> 10, d = i2 & 1023u;
      unsigned kc = d >> 5, rest = d & 31u;
      unsigned half = rest >> 4, p = rest & 15u;
      const float* src = wfc_in + (r << 10) + (kc << 5) + (p << 1);
      unsigned short h0 = f2bf(src[0]);
      unsigned short h1 = f2bf(src[1]);
      unsigned dwv;
      if (half == 0u) {
        dwv = (unsigned)h0 | ((unsigned)h1 << 16);
      } else {
        unsigned short l0 = f2bf(src[0] - bf2f(h0));
        unsigned short l1 = f2bf(src[1] - bf2f(h1));
        dwv = (unsigned)l0 | ((unsigned)l1 << 16);
      }
      wfc[i2] = dwv;
    } else if (idx < 17891328u) {            // xinit fragment-ordered
      unsigned i3 = idx - 17825792u;
      unsigned kc = i3 >> 11;
      unsigned hl = (i3 >> 10) & 1u;
      unsigned mt = (i3 >> 8) & 3u;
      unsigned ln = (i3 >> 2) & 63u;
      unsigned ep = i3 & 3u;
      unsigned rr = (mt << 4) + (ln & 15u);
      unsigned c0 = (kc << 5) + ((ln >> 4) << 3) + (ep << 1);
      const float* src = hin + (rr << 10) + c0;
      unsigned short h0 = f2bf(src[0]);
      unsigned short h1 = f2bf(src[1]);
      unsigned dwv;
      if (hl == 0u) {
        dwv = (unsigned)h0 | ((unsigned)h1 << 16);
      } else {
        unsigned short l0 = f2bf(src[0] - bf2f(h0));
        unsigned short l1 = f2bf(src[1] - bf2f(h1));
        dwv = (unsigned)l0 | ((unsigned)l1 << 16);
      }
      xinit[i3] = dwv;
    }
  }
}

// ---------- generic grid barrier (initial use only) ----------
__device__ __forceinline__ void grid_barrier(unsigned* barp, unsigned g,
                                             int wid, int tid) {
  __syncthreads();
  if (wid == 0) {
    if (tid > 0 && tid < NBLK) {
      while (__hip_atomic_load(&barp[512 + tid], __ATOMIC_RELAXED,
                               __HIP_MEMORY_SCOPE_AGENT) < g) {
        __builtin_amdgcn_s_sleep(1);
      }
    }
    __syncthreads();
    if (tid < 8) {
      __hip_atomic_store(&barp[tid << 5], g, __ATOMIC_RELAXED, __HIP_MEMORY_SCOPE_AGENT);
    }
  } else {
    if (tid == 0) {
      __hip_atomic_store(&barp[512 + wid], g, __ATOMIC_RELAXED, __HIP_MEMORY_SCOPE_AGENT);
      while (__hip_atomic_load(&barp[(wid & 7) << 5], __ATOMIC_RELAXED,
                               __HIP_MEMORY_SCOPE_AGENT) < g) {
        __builtin_amdgcn_s_sleep(2);
      }
    }
  }
  __syncthreads();
}

// ---------- main persistent LSTM ----------
// NO LDS staging: fragment-ordered slabs let each wave load A-fragments straight
// to VGPRs, fully coalesced (2-slot register ring, compiler-counted vmcnt).
// Phase-split pipeline: the W_hh*h half of phase p+1 (operand published >=1
// phase earlier, L2-hot) is computed into acch BEFORE p+1's grid barrier, under
// the barrier-wait; only the W_ih*x half (fresh data) runs after release.
__global__ __launch_bounds__(512, 1) void lstm_main(
    const unsigned* __restrict__ wreg,
    unsigned* __restrict__ h0buf,      // [128] fragment slabs (aliases wreg low half)
    const unsigned* __restrict__ xinit,
    const unsigned* __restrict__ hzero,
    unsigned* __restrict__ rec,        // [128] fragment slabs = h1 history
    const float* __restrict__ bih, const float* __restrict__ bhh,
    unsigned* __restrict__ barp) {
  __shared__ float part_lds[8][64][16];   // 32 KB partials only

  const int tid = threadIdx.x;
  const int wid = blockIdx.x;
  const int wave = tid >> 6;
  const int lane = tid & 63;
  const int q = lane >> 4;
  const int m16 = lane & 15;
  const int pwid = ((wid & 7) << 5) | (wid >> 3);

  // ---- weight slice -> registers, pin ----
  bf16x8 whi[2][8], wlo[2][8];
  {
    const unsigned* wb = wreg + ((size_t)wid << 16) + ((size_t)wave << 13) + (lane << 3);
    #pragma unroll
    for (int l = 0; l < 2; ++l)
      #pragma unroll
      for (int kt = 0; kt < 8; ++kt) {
        const unsigned* p = wb + (l << 12) + (kt << 9);
        uint4 a0 = *(const uint4*)p;
        uint4 a1 = *(const uint4*)(p + 4);
        unpack2(a0, a1, whi[l][kt], wlo[l][kt]);
      }
    #pragma unroll
    for (int l = 0; l < 2; ++l)
      #pragma unroll
      for (int kt = 0; kt < 8; ++kt) {
        asm volatile("" : "+v"(whi[l][kt]), "+v"(wlo[l][kt]));
      }
  }

  // EW thread state (threads 0..255 own (b=tid>>2, jj=tid&3))
  const int eb = tid >> 2;
  const int ej = tid & 3;
  float creg[2] = {0.0f, 0.0f};
  float biasr[2][4] = {{0, 0, 0, 0}, {0, 0, 0, 0}};
  if (tid < 256) {
    #pragma unroll
    for (int l = 0; l < 2; ++l)
      #pragma unroll
      for (int g = 0; g < 4; ++g) {
        int col = (g << 10) + (pwid << 2) + ej;
        biasr[l][g] = bih[(l << 12) + col] + bhh[(l << 12) + col];
      }
  }

  grid_barrier(barp, 1u, wid, tid);
  __builtin_amdgcn_fence(__ATOMIC_ACQUIRE, "agent");

  // per-lane slab byte base: chunk (wave*4+j): + j<<13 ; mt: + mt<<10 ; lo: +4096
  const unsigned abase = ((unsigned)wave << 15) + ((unsigned)lane << 4);
  const int pcol = ((m16 & 3) << 2) | (m16 >> 2);  // partials col perm (b128 reduce)
  const f32x4 fzero = {0.0f, 0.0f, 0.0f, 0.0f};

  uint4 fh[2][4], fl[2][4];  // 2-slot fragment ring (static indices only)

  #define LOADC(slot_, srcp_, j_)                                              \
    { _Pragma("unroll")                                                        \
      for (int mtq = 0; mtq < 4; ++mtq) {                                      \
        const char* pb = (const char*)(srcp_) + abase + ((j_) << 13) + (mtq << 10); \
        fh[slot_][mtq] = *(const uint4*)pb;                                    \
        fl[slot_][mtq] = *(const uint4*)(pb + 4096);                           \
      } }

  #define MFMA3(accv_, sl_, L_, KW_)                                           \
    { _Pragma("unroll")                                                        \
      for (int mtq = 0; mtq < 4; ++mtq) {                                      \
        bf16x8 ah = as_bf(fh[sl_][mtq]);                                       \
        bf16x8 al = as_bf(fl[sl_][mtq]);                                       \
        accv_[mtq] = __builtin_amdgcn_mfma_f32_16x16x32_bf16(ah, whi[L_][KW_], accv_[mtq], 0, 0, 0); \
        accv_[mtq] = __builtin_amdgcn_mfma_f32_16x16x32_bf16(ah, wlo[L_][KW_], accv_[mtq], 0, 0, 0); \
        accv_[mtq] = __builtin_amdgcn_mfma_f32_16x16x32_bf16(al, whi[L_][KW_], accv_[mtq], 0, 0, 0); \
      } }

  // hs-partials of the upcoming phase; (0,0) has h=0 -> zero
  f32x4 acch[4];
  #pragma unroll
  for (int mt = 0; mt < 4; ++mt) acch[mt] = fzero;

  for (int t = 0; t < 128; ++t) {
    #pragma unroll
    for (int l = 0; l < 2; ++l) {
      const unsigned* srcx;
      unsigned* dst;
      if (l == 0) {
        srcx = (t == 0) ? xinit : rec + ((t - 1) << 16);
        dst = h0buf + (t << 16);
      } else {
        srcx = h0buf + (t << 16);
        dst = rec + (t << 16);
      }
      const bool last = (t == 127) && (l == 1);
      // NEXT phase's hs slab (published >=1 barrier ago -> visible, L2-hot)
      const unsigned* nh = (l == 0)
          ? ((t == 0) ? hzero : rec + ((t - 1) << 16))
          : (h0buf + (t << 16));

      // ---- xs half: acc = acch + x @ W_ih^T slice ----
      f32x4 acc[4];
      #pragma unroll
      for (int mt = 0; mt < 4; ++mt) acc[mt] = acch[mt];

      LOADC(0, srcx, 0)
      LOADC(1, srcx, 1)
      MFMA3(acc, 0, l, 4)
      LOADC(0, srcx, 2)
      MFMA3(acc, 1, l, 5)
      LOADC(1, srcx, 3)
      MFMA3(acc, 0, l, 6)
      MFMA3(acc, 1, l, 7)

      // partials -> LDS
      #pragma unroll
      for (int mt = 0; mt < 4; ++mt)
        #pragma unroll
        for (int r = 0; r < 4; ++r)
          part_lds[wave][(mt << 4) + (q << 2) + r][pcol] = acc[mt][r];
      asm volatile("s_waitcnt lgkmcnt(0)" ::: "memory");
      __builtin_amdgcn_s_barrier();      // A1: partials visible
      asm volatile("" ::: "memory");

      // reduce + elementwise + publish (fragment-ordered address)
      if (tid < 256) {
        f32x4 s4 = {biasr[l][0], biasr[l][1], biasr[l][2], biasr[l][3]};
        #pragma unroll
        for (int w = 0; w < 8; ++w)
          s4 += *(const f32x4*)&part_lds[w][eb][ej << 2];
        float ig = sigm(s4.x);
        float fg = sigm(s4.y);
        float gv = tanh_f(s4.z);
        float og = sigm(s4.w);
        float cn = fg * creg[l] + ig * gv;
        float hn = og * tanh_f(cn);
        creg[l] = cn;
        unsigned hiv = f2bf(hn);
        unsigned lov = f2bf(hn - bf2f((unsigned short)hiv));
        unsigned phi = __shfl_xor(hiv, 1);
        unsigned plo = __shfl_xor(lov, 1);
        unsigned dw = (ej & 1) ? (plo | (lov << 16)) : (hiv | (phi << 16));
        int idx = ((pwid >> 3) << 11) + ((ej & 1) << 10) + ((eb >> 4) << 8)
                + (((((pwid & 7) >> 1) << 4) + (eb & 15)) << 2)
                + ((pwid & 1) << 1) + (ej >> 1);
        __hip_atomic_store(&dst[idx], dw, __ATOMIC_RELAXED, __HIP_MEMORY_SCOPE_AGENT);
      }
      if (last) return;

      // ---- tail: prefetch next-phase hs, ack publish, arrive early ----
      LOADC(0, nh, 0)
      LOADC(1, nh, 1)
      if (tid < 256) {
        // 16 newer loads outstanding -> the older publish store has retired
        asm volatile("s_waitcnt vmcnt(16)" ::: "memory");
      }
      asm volatile("" ::: "memory");
      __builtin_amdgcn_s_barrier();      // A2: all publishes acked
      asm volatile("" ::: "memory");

      const unsigned gph = (unsigned)(2 * t + l + 2);
      if (wid != 0 && tid == 0) {
        __hip_atomic_store(&barp[512 + wid], gph, __ATOMIC_RELAXED,
                           __HIP_MEMORY_SCOPE_AGENT);
      }

      // ---- hs precompute for next phase (runs under the barrier wait) ----
      #pragma unroll
      for (int mt = 0; mt < 4; ++mt) acch[mt] = fzero;
      {
        MFMA3(acch, 0, l ^ 1, 0)
        LOADC(0, nh, 2)
        MFMA3(acch, 1, l ^ 1, 1)
        LOADC(1, nh, 3)
        MFMA3(acch, 0, l ^ 1, 2)
        MFMA3(acch, 1, l ^ 1, 3)
      }

      // ---- release ----
      if (wid == 0) {
        if (tid > 0 && tid < NBLK) {
          while (__hip_atomic_load(&barp[512 + tid], __ATOMIC_RELAXED,
                                   __HIP_MEMORY_SCOPE_AGENT) < gph) {
            __builtin_amdgcn_s_sleep(1);
          }
        }
        asm volatile("" ::: "memory");
        __builtin_amdgcn_s_barrier();
        asm volatile("" ::: "memory");
        if (tid < 8) {
          __hip_atomic_store(&barp[tid << 5], gph, __ATOMIC_RELAXED,
                             __HIP_MEMORY_SCOPE_AGENT);
        }
      } else {
        if (tid == 0) {
          while (__hip_atomic_load(&barp[(wid & 7) << 5], __ATOMIC_RELAXED,
                                   __HIP_MEMORY_SCOPE_AGENT) < gph) {
            __builtin_amdgcn_s_sleep(2);
          }
        }
      }
      asm volatile("" ::: "memory");
      __builtin_amdgcn_s_barrier();      // B: release
      asm volatile("" ::: "memory");
    }
  }
  #undef LOADC
  #undef MFMA3
}

// ---------- FC: out[8192,1024] = rec @ Wfc^T + b_fc ----------
// A (rec) read DIRECT from fragment-ordered slabs (coalesced, no LDS);
// B (wfc) staged via LDS from the interleaved layout (r3-proven path).
__global__ __launch_bounds__(256) void fc_kernel(
    const unsigned* __restrict__ rec, const unsigned* __restrict__ wfc,
    const float* __restrict__ bfc, float* __restrict__ out) {
  __shared__ unsigned w_lds[128 * 36];
  const int tid = threadIdx.x;
  const int wave = tid >> 6;
  const int lane = tid & 63;
  const int q = lane >> 4;
  const int m16 = lane & 15;
  const int m0 = (blockIdx.x >> 3) << 7;
  const int n0 = (blockIdx.x & 7) << 7;
  const f32x4 fzero = {0.0f, 0.0f, 0.0f, 0.0f};

  f32x4 acc[2][8];
  for (int mt = 0; mt < 2; ++mt)
    for (int nt = 0; nt < 8; ++nt) acc[mt][nt] = fzero;

  for (int kc = 0; kc < 32; ++kc) {
    __syncthreads();
    #pragma unroll
    for (int i = 0; i < 4; ++i) {
      int c = (i << 8) + tid;
      int r = c >> 3;
      int cc = (c & 7) << 2;
      *(uint4*)(w_lds + r * 36 + cc) = *(const uint4*)(wfc + ((n0 + r) << 10) + (kc << 5) + cc);
    }
    __syncthreads();

    bf16x8 ahi[2], alo[2];
    #pragma unroll
    for (int mtl = 0; mtl < 2; ++mtl) {
      int grow = m0 + (wave << 5) + (mtl << 4);
      const char* ab = (const char*)rec + ((size_t)(grow >> 6) << 18)
                     + ((size_t)kc << 13) + (((grow >> 4) & 3) << 10) + (lane << 4);
      ahi[mtl] = as_bf(*(const uint4*)ab);
      alo[mtl] = as_bf(*(const uint4*)(ab + 4096));
    }
    #pragma unroll
    for (int nt = 0; nt < 8; ++nt) {
      int wrow = (nt << 4) + m16;
      bf16x8 bhi = as_bf(*(const uint4*)(w_lds + wrow * 36 + (q << 2)));
      bf16x8 blo = as_bf(*(const uint4*)(w_lds + wrow * 36 + 16 + (q << 2)));
      #pragma unroll
      for (int mt = 0; mt < 2; ++mt) {
        acc[mt][nt] = __builtin_amdgcn_mfma_f32_16x16x32_bf16(ahi[mt], bhi, acc[mt][nt], 0, 0, 0);
        acc[mt][nt] = __builtin_amdgcn_mfma_f32_16x16x32_bf16(ahi[mt], blo, acc[mt][nt], 0, 0, 0);
        acc[mt][nt] = __builtin_amdgcn_mfma_f32_16x16x32_bf16(alo[mt], bhi, acc[mt][nt], 0, 0, 0);
      }
    }
  }
  #pragma unroll
  for (int mt = 0; mt < 2; ++mt)
    #pragma unroll
    for (int nt = 0; nt < 8; ++nt) {
      int n = n0 + (nt << 4) + m16;
      float bv = bfc[n];
      #pragma unroll
      for (int r2 = 0; r2 < 4; ++r2) {
        int m = m0 + (wave << 5) + (mt << 4) + (q << 2) + r2;
        out[(m << 10) + n] = acc[mt][nt][r2] + bv;
      }
    }
}

// ---------- launch ----------
extern "C" void kernel_launch(void* const* d_in, const int* in_sizes, int n_in,
                              void* d_out, int out_size, void* d_ws, size_t ws_size,
                              hipStream_t stream) {
  const float* h_in = (const float*)d_in[0];
  const float* W_ih = (const float*)d_in[1];
  const float* W_hh = (const float*)d_in[2];
  const float* b_ih = (const float*)d_in[3];
  const float* b_hh = (const float*)d_in[4];
  const float* W_fc = (const float*)d_in[5];
  const float* b_fc = (const float*)d_in[6];
  (void)in_sizes; (void)n_in; (void)out_size; (void)ws_size;

  char* ws = (char*)d_ws;
  unsigned* wreg  = (unsigned*)(ws + 0);          // 64 MB
  unsigned* h0buf = (unsigned*)(ws + 0);          // 32 MB, aliases wreg lower half
  unsigned* wfc   = (unsigned*)(ws + 67108864);   // 4 MB (interleaved)
  unsigned* xinit = (unsigned*)(ws + 71303168);   // 256 KB (fragment-ordered)
  unsigned* hzero = (unsigned*)(ws + 71565312);   // 256 KB zeros
  unsigned* barp  = (unsigned*)(ws + 71827456);   // gens + flags
  unsigned* rec   = (unsigned*)(ws + 72616192);   // 32 MB (fragment-ordered)
  float*    out   = (float*)d_out;

  (void)hipMemsetAsync(ws + 71565312, 0, 262144 + 266240, stream);

  prep_kernel<<<dim3(8736), dim3(256), 0, stream>>>(W_ih, W_hh, W_fc, h_in,
                                                    wreg, wfc, xinit);

  lstm_main<<<dim3(NBLK), dim3(512), 0, stream>>>(wreg, h0buf, xinit, hzero, rec,
                                                  b_ih, b_hh, barp);

  fc_kernel<<<dim3(512), dim3(256), 0, stream>>>(rec, wfc, b_fc, out);
}